// Round 3
// baseline (880.547 us; speedup 1.0000x reference)
//
#include <hip/hip_runtime.h>

#define NN   4096
#define FIN  3000
#define MAXN 128

typedef unsigned short u16;

__device__ __forceinline__ float bf2f(u16 u) { union { unsigned int i; float f; } v; v.i = ((unsigned int)u) << 16; return v.f; }
__device__ __forceinline__ float bflo(unsigned int w) { union { unsigned int i; float f; } v; v.i = w << 16; return v.f; }
__device__ __forceinline__ float bfhi(unsigned int w) { union { unsigned int i; float f; } v; v.i = w & 0xFFFF0000u; return v.f; }
__device__ __forceinline__ u16 f2bf(float f) {
    union { float f; unsigned int i; } v; v.f = f;
    return (u16)((v.i + 0x7FFFu + ((v.i >> 16) & 1u)) >> 16);
}

// ---- dtype detector: bf16 N(0,1) u16s have exponent ~127; f32-as-u16 halves are random.
__global__ __launch_bounds__(256) void k_detect(const u16* __restrict__ feat, int* __restrict__ flag)
{
    __shared__ int tot;
    if (threadIdx.x == 0) tot = 0;
    __syncthreads();
    int ins = 0;
    for (int i = threadIdx.x; i < 16384; i += 256) {
        u16 u = feat[i];
        int e = (u >> 7) & 0xFF;
        if (u != 0 && (e < 90 || e > 160)) ins++;
    }
    atomicAdd(&tot, ins);
    __syncthreads();
    if (threadIdx.x == 0) *flag = (tot > 1024) ? 1 : 0;   // 1 = inputs are f32
}

// ---- convert 16 weight tensors -> f32 arena (blockIdx.y = segment) ----
__global__ __launch_bounds__(256) void k_convw(const int* __restrict__ flag,
    const void* s0, const void* s1, const void* s2, const void* s3,
    const void* s4, const void* s5, const void* s6, const void* s7,
    const void* s8, const void* s9, const void* s10, const void* s11,
    const void* s12, const void* s13, const void* s14, const void* s15,
    float* __restrict__ dst)
{
    const void* srcs[16] = {s0,s1,s2,s3,s4,s5,s6,s7,s8,s9,s10,s11,s12,s13,s14,s15};
    const int offs[16] = {0,192000,196096,196160,196224,212608,212864,245632,245760,253952,254016,262208,262336,270528,270592,274688};
    const int ns[16]   = {192000,4096,64,64,16384,256,32768,128,8192,64,8192,128,8192,64,4096,1};
    int seg = blockIdx.y;
    int i = blockIdx.x * 256 + threadIdx.x;
    if (i >= ns[seg]) return;
    float v = (*flag) ? ((const float*)srcs[seg])[i] : bf2f(((const u16*)srcs[seg])[i]);
    dst[offs[seg] + i] = v;
}

// ---- convert weight2 -> f32 in d_ws (survives the arena clobber) ----
__global__ __launch_bounds__(256) void k_convw2(const int* __restrict__ flag,
    const void* __restrict__ src, float* __restrict__ dst)
{
    int i = blockIdx.x * 256 + threadIdx.x;
    if (i >= 192000) return;
    dst[i] = (*flag) ? ((const float*)src)[i] : bf2f(((const u16*)src)[i]);
}

// ---- ordered CSR build (prefix-scan, deterministic, sorted) for adj / graph_neigh ----
__global__ __launch_bounds__(256) void k_build_csr(const int* __restrict__ flag,
    const void* __restrict__ Av, const void* __restrict__ Gv,
    int* __restrict__ aCnt, int* __restrict__ aIdx,
    int* __restrict__ gCnt, int* __restrict__ gIdx)
{
    bool isf = (*flag != 0);
    const void* M = blockIdx.y ? Gv : Av;
    int* cnt = blockIdx.y ? gCnt : aCnt;
    int* idx = blockIdx.y ? gIdx : aIdx;
    int row = blockIdx.x, t = threadIdx.x;
    int c0 = t * 16;
    unsigned int mask = 0; int my = 0;
    if (isf) {
        const float* r = (const float*)M + (size_t)row * NN + c0;
        #pragma unroll
        for (int j = 0; j < 16; j++) if (r[j] != 0.f) { mask |= 1u << j; my++; }
    } else {
        const u16* r = (const u16*)M + (size_t)row * NN + c0;
        #pragma unroll
        for (int j = 0; j < 16; j++) if (r[j] != 0) { mask |= 1u << j; my++; }
    }
    __shared__ int sc[256];
    sc[t] = my;
    __syncthreads();
    for (int d = 1; d < 256; d <<= 1) {
        int v = (t >= d) ? sc[t - d] : 0;
        __syncthreads();
        sc[t] += v;
        __syncthreads();
    }
    int pos = sc[t] - my;
    for (int j = 0; j < 16; j++) {
        if (mask & (1u << j)) {
            if (pos < MAXN) idx[(size_t)row * MAXN + pos] = c0 + j;
            pos++;
        }
    }
    if (t == 0) { int total = sc[255]; cnt[row] = (total < MAXN) ? total : MAXN; }
}

// ---- X = feat @ weight1 (dual-dtype feat), one row per 256-thread block ----
__global__ __launch_bounds__(256) void k_featgemm(const int* __restrict__ flag,
    const void* __restrict__ F0v, const void* __restrict__ F1v,
    const float* __restrict__ W1f, float* __restrict__ X0, float* __restrict__ X1)
{
    bool isf = (*flag != 0);
    const void* Fv = blockIdx.y ? F1v : F0v;
    float* X = blockIdx.y ? X1 : X0;
    int row = blockIdx.x;
    int lane = threadIdx.x & 63, grp = threadIdx.x >> 6;
    float acc = 0.f;
    if (isf) {
        const float4* frow = (const float4*)((const float*)Fv + (size_t)row * FIN); // 750 float4
        for (int c = grp; c < FIN / 4; c += 4) {
            float4 v = frow[c];
            const float* wp = W1f + (size_t)(c * 4) * 64 + lane;
            acc += v.x * wp[0 * 64];
            acc += v.y * wp[1 * 64];
            acc += v.z * wp[2 * 64];
            acc += v.w * wp[3 * 64];
        }
    } else {
        const uint4* frow = (const uint4*)((const u16*)Fv + (size_t)row * FIN); // 375 uint4
        for (int c = grp; c < FIN / 8; c += 4) {
            uint4 v = frow[c];
            const float* wp = W1f + (size_t)(c * 8) * 64 + lane;
            acc += bflo(v.x) * wp[0 * 64];
            acc += bfhi(v.x) * wp[1 * 64];
            acc += bflo(v.y) * wp[2 * 64];
            acc += bfhi(v.y) * wp[3 * 64];
            acc += bflo(v.z) * wp[4 * 64];
            acc += bfhi(v.z) * wp[5 * 64];
            acc += bflo(v.w) * wp[6 * 64];
            acc += bfhi(v.w) * wp[7 * 64];
        }
    }
    __shared__ float red[4][64];
    red[grp][lane] = acc;
    __syncthreads();
    if (threadIdx.x < 64) {
        int l = threadIdx.x;
        X[(size_t)row * 64 + l] = red[0][l] + red[1][l] + red[2][l] + red[3][l];
    }
}

// ---- Wh = X @ att_W; s = Wh@a_src; d = Wh@a_dst (all-f32) ----
__global__ __launch_bounds__(64) void k_whsd(
    const float* __restrict__ X1, const float* __restrict__ X2,
    const float* __restrict__ AW, const float* __restrict__ asrc, const float* __restrict__ adst,
    float* __restrict__ Wh1, float* __restrict__ Wh2,
    float* __restrict__ s1, float* __restrict__ s2,
    float* __restrict__ d1, float* __restrict__ d2)
{
    const float* X = blockIdx.y ? X2 : X1;
    float* Wh = blockIdx.y ? Wh2 : Wh1;
    float* sv = blockIdx.y ? s2 : s1;
    float* dv = blockIdx.y ? d2 : d1;
    int row = blockIdx.x, c = threadIdx.x;
    __shared__ float x[64];
    x[c] = X[(size_t)row * 64 + c];
    __syncthreads();
    float acc = 0.f;
    #pragma unroll 16
    for (int k = 0; k < 64; k++) acc += x[k] * AW[k * 64 + c];
    Wh[(size_t)row * 64 + c] = acc;
    float vs = acc * asrc[c];
    float vd = acc * adst[c];
    #pragma unroll
    for (int off = 32; off > 0; off >>= 1) { vs += __shfl_down(vs, off); vd += __shfl_down(vd, off); }
    if (c == 0) { sv[row] = vs; dv[row] = vd; }
}

// ---- masked softmax (rank-1 scores) + P @ Wh over CSR neighbors ----
__global__ __launch_bounds__(128) void k_attn(
    const int* __restrict__ cnt, const int* __restrict__ idx,
    const float* __restrict__ s1, const float* __restrict__ s2,
    const float* __restrict__ d1, const float* __restrict__ d2,
    const float* __restrict__ Wh1, const float* __restrict__ Wh2,
    float* __restrict__ A1, float* __restrict__ A2)
{
    const float* sp = blockIdx.y ? s2 : s1;
    const float* dp = blockIdx.y ? d2 : d1;
    const float* Wh = blockIdx.y ? Wh2 : Wh1;
    float* A = blockIdx.y ? A2 : A1;
    int row = blockIdx.x, tid = threadIdx.x;
    int n = cnt[row];
    __shared__ int js[MAXN];
    __shared__ float ps[MAXN];
    __shared__ float red2[2];
    __shared__ float ared[2][64];
    for (int k = tid; k < n; k += 128) js[k] = idx[(size_t)row * MAXN + k];
    __syncthreads();
    float si = sp[row];
    float m = -3.0e38f;
    for (int k = tid; k < n; k += 128) {
        float e = si + dp[js[k]];
        e = e > 0.f ? e : 0.2f * e;   // LeakyReLU(0.2)
        ps[k] = e;
        m = fmaxf(m, e);
    }
    #pragma unroll
    for (int off = 32; off > 0; off >>= 1) m = fmaxf(m, __shfl_down(m, off));
    if ((tid & 63) == 0) red2[tid >> 6] = m;
    __syncthreads();
    m = fmaxf(red2[0], red2[1]);
    __syncthreads();
    float zz = 0.f;
    for (int k = tid; k < n; k += 128) {
        float p = __expf(ps[k] - m);
        ps[k] = p;
        zz += p;
    }
    #pragma unroll
    for (int off = 32; off > 0; off >>= 1) zz += __shfl_down(zz, off);
    if ((tid & 63) == 0) red2[tid >> 6] = zz;
    __syncthreads();
    float Z = red2[0] + red2[1];
    Z = fmaxf(Z, 1e-20f);           // guard 0/0
    int f = tid & 63, half = tid >> 6;
    float acc = 0.f;
    for (int k = half; k < n; k += 2) acc += ps[k] * Wh[(size_t)js[k] * 64 + f];
    ared[half][f] = acc;
    __syncthreads();
    if (tid < 64) A[(size_t)row * 64 + f] = (ared[0][f] + ared[1][f]) / Z;
}

// ---- 3-layer MLP 64->256->128->64; writes z (f32) and hiden_emb (dual-dtype, y==0) ----
__global__ __launch_bounds__(256) void k_mlp(const int* __restrict__ flag,
    const float* __restrict__ A1, const float* __restrict__ A2,
    const float* __restrict__ W1, const float* __restrict__ b1,
    const float* __restrict__ W2, const float* __restrict__ b2,
    const float* __restrict__ W3, const float* __restrict__ b3,
    float* __restrict__ Z1, float* __restrict__ Z2, void* __restrict__ hidenv)
{
    const float* A = blockIdx.y ? A2 : A1;
    float* Z = blockIdx.y ? Z2 : Z1;
    int row = blockIdx.x, tid = threadIdx.x;
    __shared__ float x[64], h1[256], h2[128];
    if (tid < 64) x[tid] = A[(size_t)row * 64 + tid];
    __syncthreads();
    {
        float a = b1[tid];
        #pragma unroll 8
        for (int k = 0; k < 64; k++) a += x[k] * W1[k * 256 + tid];
        h1[tid] = fmaxf(a, 0.f);
    }
    __syncthreads();
    if (tid < 128) {
        float a = b2[tid];
        #pragma unroll 8
        for (int k = 0; k < 256; k++) a += h1[k] * W2[k * 128 + tid];
        h2[tid] = fmaxf(a, 0.f);
    }
    __syncthreads();
    if (tid < 64) {
        float a = b3[tid];
        #pragma unroll 8
        for (int k = 0; k < 128; k++) a += h2[k] * W3[k * 64 + tid];
        Z[(size_t)row * 64 + tid] = a;
        if (blockIdx.y == 0) {
            size_t ei = (size_t)row * 64 + tid;
            if (*flag) ((float*)hidenv)[ei] = a;
            else       ((u16*)hidenv)[ei] = f2bf(a);
        }
    }
}

// ---- T = adj @ z over CSR ----
__global__ __launch_bounds__(64) void k_spmm(
    const int* __restrict__ cnt, const int* __restrict__ idx,
    const float* __restrict__ Z, float* __restrict__ T)
{
    int row = blockIdx.x, f = threadIdx.x;
    int n = cnt[row];
    const int* ir = idx + (size_t)row * MAXN;
    float acc = 0.f;
    for (int k = 0; k < n; k++) acc += Z[(size_t)ir[k] * 64 + f];
    T[(size_t)row * 64 + f] = acc;
}

// ---- H = T @ weight2 -> out (dual-dtype store), 8 rows/block ----
__global__ __launch_bounds__(256) void k_hgemm(const int* __restrict__ flag,
    const float* __restrict__ T, const float* __restrict__ W2f, void* __restrict__ outv)
{
    bool isf = (*flag != 0);
    int r0 = blockIdx.x * 8, tid = threadIdx.x;
    __shared__ float tt[8][64];
    for (int i = tid; i < 512; i += 256) tt[i >> 6][i & 63] = T[(size_t)r0 * 64 + i];
    __syncthreads();
    for (int c = tid; c < FIN; c += 256) {
        float a[8] = {0,0,0,0,0,0,0,0};
        #pragma unroll 8
        for (int k = 0; k < 64; k++) {
            float w = W2f[(size_t)k * FIN + c];
            #pragma unroll
            for (int i = 0; i < 8; i++) a[i] += tt[i][k] * w;
        }
        #pragma unroll
        for (int i = 0; i < 8; i++) {
            size_t ei = 262144 + (size_t)(r0 + i) * FIN + c;
            if (isf) ((float*)outv)[ei] = a[i];
            else     ((u16*)outv)[ei] = f2bf(a[i]);
        }
    }
}

// ---- readout: mean over graph_neigh nbrs of relu(z), L2 normalize, sigmoid ----
__global__ __launch_bounds__(64) void k_readout(
    const int* __restrict__ cnt, const int* __restrict__ idx,
    const float* __restrict__ Z1, const float* __restrict__ Z2,
    float* __restrict__ G1, float* __restrict__ G2)
{
    const float* Z = blockIdx.y ? Z2 : Z1;
    float* G = blockIdx.y ? G2 : G1;
    int row = blockIdx.x, f = threadIdx.x;
    int n = cnt[row];
    const int* ir = idx + (size_t)row * MAXN;
    float acc = 0.f;
    for (int k = 0; k < n; k++) acc += fmaxf(Z[(size_t)ir[k] * 64 + f], 0.f);
    acc /= (float)(n > 0 ? n : 1);
    float sq = acc * acc;
    #pragma unroll
    for (int off = 32; off > 0; off >>= 1) sq += __shfl_down(sq, off);
    sq = __shfl(sq, 0);
    float nrm = fmaxf(sqrtf(sq), 1e-12f);
    float v = acc / nrm;
    G[(size_t)row * 64 + f] = 1.f / (1.f + __expf(-v));
}

// ---- discriminator MLP 64->128->64 on {relu(z), relu(z_a), g, g_a} ----
__global__ __launch_bounds__(128) void k_dmlp(
    const float* __restrict__ z, const float* __restrict__ za,
    const float* __restrict__ g, const float* __restrict__ ga,
    const float* __restrict__ W1, const float* __restrict__ b1,
    const float* __restrict__ W2, const float* __restrict__ b2,
    float* __restrict__ De, float* __restrict__ Dea,
    float* __restrict__ Dg, float* __restrict__ Dga)
{
    int w = blockIdx.y;
    const float* X = (w == 0) ? z : (w == 1) ? za : (w == 2) ? g : ga;
    float* O = (w == 0) ? De : (w == 1) ? Dea : (w == 2) ? Dg : Dga;
    int doRelu = (w < 2);
    int row = blockIdx.x, tid = threadIdx.x;
    __shared__ float x[64], h1[128];
    if (tid < 64) { float v = X[(size_t)row * 64 + tid]; x[tid] = doRelu ? fmaxf(v, 0.f) : v; }
    __syncthreads();
    {
        float a = b1[tid];
        #pragma unroll 8
        for (int k = 0; k < 64; k++) a += x[k] * W1[k * 128 + tid];
        h1[tid] = fmaxf(a, 0.f);
    }
    __syncthreads();
    if (tid < 64) {
        float a = b2[tid];
        #pragma unroll 8
        for (int k = 0; k < 128; k++) a += h1[k] * W2[k * 64 + tid];
        O[(size_t)row * 64 + tid] = a;
    }
}

// ---- bilinear: out = x . (bil_W @ y) + b ; dual-dtype store ----
__global__ __launch_bounds__(64) void k_bilin(const int* __restrict__ flag,
    const float* __restrict__ De, const float* __restrict__ Dea,
    const float* __restrict__ Dg, const float* __restrict__ Dga,
    const float* __restrict__ BW, const float* __restrict__ bb, void* __restrict__ outv)
{
    int w = blockIdx.y;
    const float* X = (w == 0 || w == 3) ? De : Dea;
    const float* Y = (w <= 1) ? Dg : Dga;
    size_t bse = (w <= 1) ? (size_t)12550144 : (size_t)12558336;
    int col = (w == 0 || w == 2) ? 0 : 1;
    int row = blockIdx.x, k = threadIdx.x;
    __shared__ float x[64], y[64];
    x[k] = X[(size_t)row * 64 + k];
    y[k] = Y[(size_t)row * 64 + k];
    __syncthreads();
    float wv = 0.f;
    #pragma unroll 8
    for (int j = 0; j < 64; j++) wv += BW[k * 64 + j] * y[j];
    float v = x[k] * wv;
    #pragma unroll
    for (int off = 32; off > 0; off >>= 1) v += __shfl_down(v, off);
    if (k == 0) {
        float r = v + bb[0];
        size_t ei = bse + (size_t)row * 2 + col;
        if (*flag) ((float*)outv)[ei] = r;
        else       ((u16*)outv)[ei] = f2bf(r);
    }
}

extern "C" void kernel_launch(void* const* d_in, const int* in_sizes, int n_in,
                              void* d_out, int out_size, void* d_ws, size_t ws_size,
                              hipStream_t stream) {
    const void* feat   = d_in[0];
    const void* feat_a = d_in[1];
    const void* adj    = d_in[2];
    const void* gn     = d_in[3];
    const void* w1     = d_in[4];
    const void* w2     = d_in[5];
    const void* attW   = d_in[6];
    const void* a_src  = d_in[7];
    const void* a_dst  = d_in[8];
    const void* mW1    = d_in[9];
    const void* mb1    = d_in[10];
    const void* mW2    = d_in[11];
    const void* mb2    = d_in[12];
    const void* mW3    = d_in[13];
    const void* mb3    = d_in[14];
    const void* dW1    = d_in[15];
    const void* db1    = d_in[16];
    const void* dW2    = d_in[17];
    const void* db2    = d_in[18];
    const void* bW     = d_in[19];
    const void* bb     = d_in[20];
    (void)in_sizes; (void)n_in; (void)out_size;

    // ---- d_ws: flag + T + w2f  (~1.8 MB total; minimal footprint) ----
    char* wsb = (char*)d_ws;
    int*   flag = (int*)wsb;                        // 4 B (pad 256)
    float* T    = (float*)(wsb + 256);              // 1,048,576 B
    float* w2f  = (float*)(wsb + 256 + 1048576);    // 768,000 B
    (void)ws_size;

    // ---- scratch arena at dtype-independent byte window of d_out:
    // bytes [1,048,576 , 21,200,000) lie inside the h output region for BOTH
    // bf16 (h bytes [524288,25100288)) and f32 (h bytes [1048576,50200576)),
    // and are fully overwritten by k_hgemm at the end.
    char* sc = (char*)d_out + 1048576;
    size_t soff = 0;
    auto salloc = [&](size_t nbytes) -> void* {
        void* p = (void*)(sc + soff);
        soff += (nbytes + 255) & ~(size_t)255;
        return p;
    };
    const size_t NV = (size_t)NN * 64;
    float* wA   = (float*)salloc((size_t)274689 * 4);  // 16-segment f32 weight arena
    int*   aCnt = (int*)salloc(NN * 4);
    int*   gCnt = (int*)salloc(NN * 4);
    int*   aIdx = (int*)salloc((size_t)NN * MAXN * 4);
    int*   gIdx = (int*)salloc((size_t)NN * MAXN * 4);
    float* X1  = (float*)salloc(NV * 4);
    float* X2  = (float*)salloc(NV * 4);
    float* Wh1 = (float*)salloc(NV * 4);
    float* Wh2 = (float*)salloc(NV * 4);
    float* A1  = (float*)salloc(NV * 4);
    float* A2  = (float*)salloc(NV * 4);
    float* z   = (float*)salloc(NV * 4);
    float* za  = (float*)salloc(NV * 4);
    float* g   = (float*)salloc(NV * 4);
    float* ga  = (float*)salloc(NV * 4);
    float* De  = (float*)salloc(NV * 4);
    float* Dea = (float*)salloc(NV * 4);
    float* Dg  = (float*)salloc(NV * 4);
    float* Dga = (float*)salloc(NV * 4);
    float* s1  = (float*)salloc(NN * 4);
    float* s2  = (float*)salloc(NN * 4);
    float* d1  = (float*)salloc(NN * 4);
    float* d2  = (float*)salloc(NN * 4);
    // soff ~= 20.1 MB < 20.15 MB window: fits.

    float* w1f   = wA + 0;
    float* attWf = wA + 192000;
    float* asrcf = wA + 196096;
    float* adstf = wA + 196160;
    float* mW1f  = wA + 196224;
    float* mb1f  = wA + 212608;
    float* mW2f  = wA + 212864;
    float* mb2f  = wA + 245632;
    float* mW3f  = wA + 245760;
    float* mb3f  = wA + 253952;
    float* dW1f  = wA + 254016;
    float* db1f  = wA + 262208;
    float* dW2f  = wA + 262336;
    float* db2f  = wA + 270528;
    float* bWf   = wA + 270592;
    float* bbf   = wA + 274688;

    k_detect<<<1, 256, 0, stream>>>((const u16*)feat, flag);
    k_convw<<<dim3(750, 16), 256, 0, stream>>>(flag,
        w1, attW, a_src, a_dst, mW1, mb1, mW2, mb2, mW3, mb3,
        dW1, db1, dW2, db2, bW, bb, wA);
    k_convw2<<<750, 256, 0, stream>>>(flag, w2, w2f);
    k_build_csr<<<dim3(NN, 2), 256, 0, stream>>>(flag, adj, gn, aCnt, aIdx, gCnt, gIdx);
    k_featgemm<<<dim3(NN, 2), 256, 0, stream>>>(flag, feat, feat_a, w1f, X1, X2);
    k_whsd<<<dim3(NN, 2), 64, 0, stream>>>(X1, X2, attWf, asrcf, adstf, Wh1, Wh2, s1, s2, d1, d2);
    k_attn<<<dim3(NN, 2), 128, 0, stream>>>(aCnt, aIdx, s1, s2, d1, d2, Wh1, Wh2, A1, A2);
    k_mlp<<<dim3(NN, 2), 256, 0, stream>>>(flag, A1, A2, mW1f, mb1f, mW2f, mb2f, mW3f, mb3f, z, za, d_out);
    k_readout<<<dim3(NN, 2), 64, 0, stream>>>(gCnt, gIdx, z, za, g, ga);
    k_dmlp<<<dim3(NN, 4), 128, 0, stream>>>(z, za, g, ga, dW1f, db1f, dW2f, db2f, De, Dea, Dg, Dga);
    k_bilin<<<dim3(NN, 4), 64, 0, stream>>>(flag, De, Dea, Dg, Dga, bWf, bbf, d_out);
    k_spmm<<<NN, 64, 0, stream>>>(aCnt, aIdx, z, T);
    k_hgemm<<<512, 256, 0, stream>>>(flag, T, w2f, d_out);   // overwrites arena with real h
}

// Round 4
// 790.546 us; speedup vs baseline: 1.1138x; 1.1138x over previous
//
#include <hip/hip_runtime.h>

#define NN   4096
#define FIN  3000
#define MAXN 128
#define KB   48
#define FSTR 52

typedef unsigned short u16;

__device__ __forceinline__ float bf2f(u16 u) { union { unsigned int i; float f; } v; v.i = ((unsigned int)u) << 16; return v.f; }
__device__ __forceinline__ u16 f2bf(float f) {
    union { float f; unsigned int i; } v; v.f = f;
    return (u16)((v.i + 0x7FFFu + ((v.i >> 16) & 1u)) >> 16);
}

// ---- dtype detector: bf16 N(0,1) u16s have exponent ~127; f32-as-u16 halves are random.
__global__ __launch_bounds__(256) void k_detect(const u16* __restrict__ feat, int* __restrict__ flag)
{
    __shared__ int tot;
    if (threadIdx.x == 0) tot = 0;
    __syncthreads();
    int ins = 0;
    for (int i = threadIdx.x; i < 16384; i += 256) {
        u16 u = feat[i];
        int e = (u >> 7) & 0xFF;
        if (u != 0 && (e < 90 || e > 160)) ins++;
    }
    atomicAdd(&tot, ins);
    __syncthreads();
    if (threadIdx.x == 0) *flag = (tot > 1024) ? 1 : 0;   // 1 = inputs are f32
}

// ---- convert 16 weight tensors -> f32 arena (blockIdx.y = segment) ----
__global__ __launch_bounds__(256) void k_convw(const int* __restrict__ flag,
    const void* s0, const void* s1, const void* s2, const void* s3,
    const void* s4, const void* s5, const void* s6, const void* s7,
    const void* s8, const void* s9, const void* s10, const void* s11,
    const void* s12, const void* s13, const void* s14, const void* s15,
    float* __restrict__ dst)
{
    const void* srcs[16] = {s0,s1,s2,s3,s4,s5,s6,s7,s8,s9,s10,s11,s12,s13,s14,s15};
    const int offs[16] = {0,192000,196096,196160,196224,212608,212864,245632,245760,253952,254016,262208,262336,270528,270592,274688};
    const int ns[16]   = {192000,4096,64,64,16384,256,32768,128,8192,64,8192,128,8192,64,4096,1};
    int seg = blockIdx.y;
    int i = blockIdx.x * 256 + threadIdx.x;
    if (i >= ns[seg]) return;
    float v = (*flag) ? ((const float*)srcs[seg])[i] : bf2f(((const u16*)srcs[seg])[i]);
    dst[offs[seg] + i] = v;
}

// ---- convert weight2 -> f32 in d_ws (survives the arena clobber) ----
__global__ __launch_bounds__(256) void k_convw2(const int* __restrict__ flag,
    const void* __restrict__ src, float* __restrict__ dst)
{
    int i = blockIdx.x * 256 + threadIdx.x;
    if (i >= 192000) return;
    dst[i] = (*flag) ? ((const float*)src)[i] : bf2f(((const u16*)src)[i]);
}

// ---- ordered CSR build (prefix-scan, deterministic, sorted) for adj / graph_neigh ----
__global__ __launch_bounds__(256) void k_build_csr(const int* __restrict__ flag,
    const void* __restrict__ Av, const void* __restrict__ Gv,
    int* __restrict__ aCnt, int* __restrict__ aIdx,
    int* __restrict__ gCnt, int* __restrict__ gIdx)
{
    bool isf = (*flag != 0);
    const void* M = blockIdx.y ? Gv : Av;
    int* cnt = blockIdx.y ? gCnt : aCnt;
    int* idx = blockIdx.y ? gIdx : aIdx;
    int row = blockIdx.x, t = threadIdx.x;
    int c0 = t * 16;
    unsigned int mask = 0; int my = 0;
    if (isf) {
        const float* r = (const float*)M + (size_t)row * NN + c0;
        #pragma unroll
        for (int j = 0; j < 16; j++) if (r[j] != 0.f) { mask |= 1u << j; my++; }
    } else {
        const u16* r = (const u16*)M + (size_t)row * NN + c0;
        #pragma unroll
        for (int j = 0; j < 16; j++) if (r[j] != 0) { mask |= 1u << j; my++; }
    }
    __shared__ int sc[256];
    sc[t] = my;
    __syncthreads();
    for (int d = 1; d < 256; d <<= 1) {
        int v = (t >= d) ? sc[t - d] : 0;
        __syncthreads();
        sc[t] += v;
        __syncthreads();
    }
    int pos = sc[t] - my;
    for (int j = 0; j < 16; j++) {
        if (mask & (1u << j)) {
            if (pos < MAXN) idx[(size_t)row * MAXN + pos] = c0 + j;
            pos++;
        }
    }
    if (t == 0) { int total = sc[255]; cnt[row] = (total < MAXN) ? total : MAXN; }
}

// ---- X = feat @ weight1, LDS-tiled: 128 thr, 32x64 tile, K-chunks of 48, 4x4 acc ----
__global__ __launch_bounds__(128) void k_featgemm(const int* __restrict__ flag,
    const void* __restrict__ F0v, const void* __restrict__ F1v,
    const float* __restrict__ W1f, float* __restrict__ X0, float* __restrict__ X1)
{
    bool isf = (*flag != 0);
    const void* Fv = blockIdx.y ? F1v : F0v;
    float* X = blockIdx.y ? X1 : X0;
    int r0 = blockIdx.x * 32;
    int tid = threadIdx.x;
    int cg = tid & 15, rg = tid >> 4;     // 16 col-groups x 8 row-groups
    int c0 = cg * 4, rr = rg * 4;
    __shared__ float Wl[KB * 64];          // [kk][c], 12288 B
    __shared__ float Fl[32 * FSTR];        // [row][kk], pad 52 (16B-aligned rows, 2-way banks)
    float acc[4][4] = {};
    for (int k0 = 0; k0 < FIN; k0 += KB) {
        int rem = FIN - k0;
        int nk = rem < KB ? rem : KB;      // 48 or 24 (last)
        __syncthreads();
        // W chunk: nk*64 floats contiguous from W1f + k0*64; zero-fill tail
        {
            const float4* g = (const float4*)(W1f + (size_t)k0 * 64);
            int nf4 = (nk * 64) >> 2;
            #pragma unroll
            for (int j = 0; j < 6; j++) {
                int i = tid + 128 * j;     // [0,768)
                float4 v = {0.f, 0.f, 0.f, 0.f};
                if (i < nf4) v = g[i];
                ((float4*)Wl)[i] = v;
            }
        }
        // F tile: 32 rows x 48 cols
        if (isf) {
            const float* F = (const float*)Fv;
            #pragma unroll
            for (int j = 0; j < 3; j++) {
                int i = tid + 128 * j;     // [0,384), 12 f4 per row
                int row = i / 12, c4 = i % 12;
                int kk = c4 * 4;
                float4 v = {0.f, 0.f, 0.f, 0.f};
                if (kk < nk) v = *(const float4*)(F + (size_t)(r0 + row) * FIN + k0 + kk);
                *(float4*)(Fl + row * FSTR + kk) = v;
            }
        } else {
            const u16* F = (const u16*)Fv;
            for (int i = tid; i < 32 * KB; i += 128) {
                int row = i / KB, kk = i % KB;
                float v = 0.f;
                if (kk < nk) v = bf2f(F[(size_t)(r0 + row) * FIN + k0 + kk]);
                Fl[row * FSTR + kk] = v;
            }
        }
        __syncthreads();
        #pragma unroll
        for (int q = 0; q < KB; q += 4) {
            float4 w0 = *(float4*)(Wl + (q + 0) * 64 + c0);
            float4 w1 = *(float4*)(Wl + (q + 1) * 64 + c0);
            float4 w2 = *(float4*)(Wl + (q + 2) * 64 + c0);
            float4 w3 = *(float4*)(Wl + (q + 3) * 64 + c0);
            #pragma unroll
            for (int i = 0; i < 4; i++) {
                float4 f = *(float4*)(Fl + (rr + i) * FSTR + q);
                acc[i][0] += f.x * w0.x + f.y * w1.x + f.z * w2.x + f.w * w3.x;
                acc[i][1] += f.x * w0.y + f.y * w1.y + f.z * w2.y + f.w * w3.y;
                acc[i][2] += f.x * w0.z + f.y * w1.z + f.z * w2.z + f.w * w3.z;
                acc[i][3] += f.x * w0.w + f.y * w1.w + f.z * w2.w + f.w * w3.w;
            }
        }
    }
    #pragma unroll
    for (int i = 0; i < 4; i++) {
        float4 o = {acc[i][0], acc[i][1], acc[i][2], acc[i][3]};
        *(float4*)(X + (size_t)(r0 + rr + i) * 64 + c0) = o;
    }
}

// ---- Wh = X @ att_W; s = Wh@a_src; d = Wh@a_dst (all-f32) ----
__global__ __launch_bounds__(64) void k_whsd(
    const float* __restrict__ X1, const float* __restrict__ X2,
    const float* __restrict__ AW, const float* __restrict__ asrc, const float* __restrict__ adst,
    float* __restrict__ Wh1, float* __restrict__ Wh2,
    float* __restrict__ s1, float* __restrict__ s2,
    float* __restrict__ d1, float* __restrict__ d2)
{
    const float* X = blockIdx.y ? X2 : X1;
    float* Wh = blockIdx.y ? Wh2 : Wh1;
    float* sv = blockIdx.y ? s2 : s1;
    float* dv = blockIdx.y ? d2 : d1;
    int row = blockIdx.x, c = threadIdx.x;
    __shared__ float x[64];
    x[c] = X[(size_t)row * 64 + c];
    __syncthreads();
    float acc = 0.f;
    #pragma unroll 16
    for (int k = 0; k < 64; k++) acc += x[k] * AW[k * 64 + c];
    Wh[(size_t)row * 64 + c] = acc;
    float vs = acc * asrc[c];
    float vd = acc * adst[c];
    #pragma unroll
    for (int off = 32; off > 0; off >>= 1) { vs += __shfl_down(vs, off); vd += __shfl_down(vd, off); }
    if (c == 0) { sv[row] = vs; dv[row] = vd; }
}

// ---- masked softmax (rank-1 scores) + P @ Wh over CSR neighbors ----
__global__ __launch_bounds__(128) void k_attn(
    const int* __restrict__ cnt, const int* __restrict__ idx,
    const float* __restrict__ s1, const float* __restrict__ s2,
    const float* __restrict__ d1, const float* __restrict__ d2,
    const float* __restrict__ Wh1, const float* __restrict__ Wh2,
    float* __restrict__ A1, float* __restrict__ A2)
{
    const float* sp = blockIdx.y ? s2 : s1;
    const float* dp = blockIdx.y ? d2 : d1;
    const float* Wh = blockIdx.y ? Wh2 : Wh1;
    float* A = blockIdx.y ? A2 : A1;
    int row = blockIdx.x, tid = threadIdx.x;
    int n = cnt[row];
    __shared__ int js[MAXN];
    __shared__ float ps[MAXN];
    __shared__ float red2[2];
    __shared__ float ared[2][64];
    for (int k = tid; k < n; k += 128) js[k] = idx[(size_t)row * MAXN + k];
    __syncthreads();
    float si = sp[row];
    float m = -3.0e38f;
    for (int k = tid; k < n; k += 128) {
        float e = si + dp[js[k]];
        e = e > 0.f ? e : 0.2f * e;   // LeakyReLU(0.2)
        ps[k] = e;
        m = fmaxf(m, e);
    }
    #pragma unroll
    for (int off = 32; off > 0; off >>= 1) m = fmaxf(m, __shfl_down(m, off));
    if ((tid & 63) == 0) red2[tid >> 6] = m;
    __syncthreads();
    m = fmaxf(red2[0], red2[1]);
    __syncthreads();
    float zz = 0.f;
    for (int k = tid; k < n; k += 128) {
        float p = __expf(ps[k] - m);
        ps[k] = p;
        zz += p;
    }
    #pragma unroll
    for (int off = 32; off > 0; off >>= 1) zz += __shfl_down(zz, off);
    if ((tid & 63) == 0) red2[tid >> 6] = zz;
    __syncthreads();
    float Z = red2[0] + red2[1];
    Z = fmaxf(Z, 1e-20f);           // guard 0/0
    int f = tid & 63, half = tid >> 6;
    float acc = 0.f;
    for (int k = half; k < n; k += 2) acc += ps[k] * Wh[(size_t)js[k] * 64 + f];
    ared[half][f] = acc;
    __syncthreads();
    if (tid < 64) A[(size_t)row * 64 + f] = (ared[0][f] + ared[1][f]) / Z;
}

// ---- 3-layer MLP 64->256->128->64; writes z (f32) and hiden_emb (dual-dtype, y==0) ----
__global__ __launch_bounds__(256) void k_mlp(const int* __restrict__ flag,
    const float* __restrict__ A1, const float* __restrict__ A2,
    const float* __restrict__ W1, const float* __restrict__ b1,
    const float* __restrict__ W2, const float* __restrict__ b2,
    const float* __restrict__ W3, const float* __restrict__ b3,
    float* __restrict__ Z1, float* __restrict__ Z2, void* __restrict__ hidenv)
{
    const float* A = blockIdx.y ? A2 : A1;
    float* Z = blockIdx.y ? Z2 : Z1;
    int row = blockIdx.x, tid = threadIdx.x;
    __shared__ float x[64], h1[256], h2[128];
    if (tid < 64) x[tid] = A[(size_t)row * 64 + tid];
    __syncthreads();
    {
        float a = b1[tid];
        #pragma unroll 8
        for (int k = 0; k < 64; k++) a += x[k] * W1[k * 256 + tid];
        h1[tid] = fmaxf(a, 0.f);
    }
    __syncthreads();
    if (tid < 128) {
        float a = b2[tid];
        #pragma unroll 8
        for (int k = 0; k < 256; k++) a += h1[k] * W2[k * 128 + tid];
        h2[tid] = fmaxf(a, 0.f);
    }
    __syncthreads();
    if (tid < 64) {
        float a = b3[tid];
        #pragma unroll 8
        for (int k = 0; k < 128; k++) a += h2[k] * W3[k * 64 + tid];
        Z[(size_t)row * 64 + tid] = a;
        if (blockIdx.y == 0) {
            size_t ei = (size_t)row * 64 + tid;
            if (*flag) ((float*)hidenv)[ei] = a;
            else       ((u16*)hidenv)[ei] = f2bf(a);
        }
    }
}

// ---- T = adj @ z over CSR ----
__global__ __launch_bounds__(64) void k_spmm(
    const int* __restrict__ cnt, const int* __restrict__ idx,
    const float* __restrict__ Z, float* __restrict__ T)
{
    int row = blockIdx.x, f = threadIdx.x;
    int n = cnt[row];
    const int* ir = idx + (size_t)row * MAXN;
    float acc = 0.f;
    for (int k = 0; k < n; k++) acc += Z[(size_t)ir[k] * 64 + f];
    T[(size_t)row * 64 + f] = acc;
}

// ---- H = T @ weight2 -> out (dual-dtype store), 8 rows/block ----
__global__ __launch_bounds__(256) void k_hgemm(const int* __restrict__ flag,
    const float* __restrict__ T, const float* __restrict__ W2f, void* __restrict__ outv)
{
    bool isf = (*flag != 0);
    int r0 = blockIdx.x * 8, tid = threadIdx.x;
    __shared__ float tt[8][64];
    for (int i = tid; i < 512; i += 256) tt[i >> 6][i & 63] = T[(size_t)r0 * 64 + i];
    __syncthreads();
    for (int c = tid; c < FIN; c += 256) {
        float a[8] = {0,0,0,0,0,0,0,0};
        #pragma unroll 8
        for (int k = 0; k < 64; k++) {
            float w = W2f[(size_t)k * FIN + c];
            #pragma unroll
            for (int i = 0; i < 8; i++) a[i] += tt[i][k] * w;
        }
        #pragma unroll
        for (int i = 0; i < 8; i++) {
            size_t ei = 262144 + (size_t)(r0 + i) * FIN + c;
            if (isf) ((float*)outv)[ei] = a[i];
            else     ((u16*)outv)[ei] = f2bf(a[i]);
        }
    }
}

// ---- readout: mean over graph_neigh nbrs of relu(z), L2 normalize, sigmoid ----
__global__ __launch_bounds__(64) void k_readout(
    const int* __restrict__ cnt, const int* __restrict__ idx,
    const float* __restrict__ Z1, const float* __restrict__ Z2,
    float* __restrict__ G1, float* __restrict__ G2)
{
    const float* Z = blockIdx.y ? Z2 : Z1;
    float* G = blockIdx.y ? G2 : G1;
    int row = blockIdx.x, f = threadIdx.x;
    int n = cnt[row];
    const int* ir = idx + (size_t)row * MAXN;
    float acc = 0.f;
    for (int k = 0; k < n; k++) acc += fmaxf(Z[(size_t)ir[k] * 64 + f], 0.f);
    acc /= (float)(n > 0 ? n : 1);
    float sq = acc * acc;
    #pragma unroll
    for (int off = 32; off > 0; off >>= 1) sq += __shfl_down(sq, off);
    sq = __shfl(sq, 0);
    float nrm = fmaxf(sqrtf(sq), 1e-12f);
    float v = acc / nrm;
    G[(size_t)row * 64 + f] = 1.f / (1.f + __expf(-v));
}

// ---- discriminator MLP 64->128->64 on {relu(z), relu(z_a), g, g_a} ----
__global__ __launch_bounds__(128) void k_dmlp(
    const float* __restrict__ z, const float* __restrict__ za,
    const float* __restrict__ g, const float* __restrict__ ga,
    const float* __restrict__ W1, const float* __restrict__ b1,
    const float* __restrict__ W2, const float* __restrict__ b2,
    float* __restrict__ De, float* __restrict__ Dea,
    float* __restrict__ Dg, float* __restrict__ Dga)
{
    int w = blockIdx.y;
    const float* X = (w == 0) ? z : (w == 1) ? za : (w == 2) ? g : ga;
    float* O = (w == 0) ? De : (w == 1) ? Dea : (w == 2) ? Dg : Dga;
    int doRelu = (w < 2);
    int row = blockIdx.x, tid = threadIdx.x;
    __shared__ float x[64], h1[128];
    if (tid < 64) { float v = X[(size_t)row * 64 + tid]; x[tid] = doRelu ? fmaxf(v, 0.f) : v; }
    __syncthreads();
    {
        float a = b1[tid];
        #pragma unroll 8
        for (int k = 0; k < 64; k++) a += x[k] * W1[k * 128 + tid];
        h1[tid] = fmaxf(a, 0.f);
    }
    __syncthreads();
    if (tid < 64) {
        float a = b2[tid];
        #pragma unroll 8
        for (int k = 0; k < 128; k++) a += h1[k] * W2[k * 64 + tid];
        O[(size_t)row * 64 + tid] = a;
    }
}

// ---- bilinear: out = x . (bil_W @ y) + b ; dual-dtype store ----
__global__ __launch_bounds__(64) void k_bilin(const int* __restrict__ flag,
    const float* __restrict__ De, const float* __restrict__ Dea,
    const float* __restrict__ Dg, const float* __restrict__ Dga,
    const float* __restrict__ BW, const float* __restrict__ bb, void* __restrict__ outv)
{
    int w = blockIdx.y;
    const float* X = (w == 0 || w == 3) ? De : Dea;
    const float* Y = (w <= 1) ? Dg : Dga;
    size_t bse = (w <= 1) ? (size_t)12550144 : (size_t)12558336;
    int col = (w == 0 || w == 2) ? 0 : 1;
    int row = blockIdx.x, k = threadIdx.x;
    __shared__ float x[64], y[64];
    x[k] = X[(size_t)row * 64 + k];
    y[k] = Y[(size_t)row * 64 + k];
    __syncthreads();
    float wv = 0.f;
    #pragma unroll 8
    for (int j = 0; j < 64; j++) wv += BW[k * 64 + j] * y[j];
    float v = x[k] * wv;
    #pragma unroll
    for (int off = 32; off > 0; off >>= 1) v += __shfl_down(v, off);
    if (k == 0) {
        float r = v + bb[0];
        size_t ei = bse + (size_t)row * 2 + col;
        if (*flag) ((float*)outv)[ei] = r;
        else       ((u16*)outv)[ei] = f2bf(r);
    }
}

extern "C" void kernel_launch(void* const* d_in, const int* in_sizes, int n_in,
                              void* d_out, int out_size, void* d_ws, size_t ws_size,
                              hipStream_t stream) {
    const void* feat   = d_in[0];
    const void* feat_a = d_in[1];
    const void* adj    = d_in[2];
    const void* gn     = d_in[3];
    const void* w1     = d_in[4];
    const void* w2     = d_in[5];
    const void* attW   = d_in[6];
    const void* a_src  = d_in[7];
    const void* a_dst  = d_in[8];
    const void* mW1    = d_in[9];
    const void* mb1    = d_in[10];
    const void* mW2    = d_in[11];
    const void* mb2    = d_in[12];
    const void* mW3    = d_in[13];
    const void* mb3    = d_in[14];
    const void* dW1    = d_in[15];
    const void* db1    = d_in[16];
    const void* dW2    = d_in[17];
    const void* db2    = d_in[18];
    const void* bW     = d_in[19];
    const void* bb     = d_in[20];
    (void)in_sizes; (void)n_in; (void)out_size;

    // ---- d_ws: flag + T + w2f  (~1.8 MB total; minimal footprint) ----
    char* wsb = (char*)d_ws;
    int*   flag = (int*)wsb;                        // 4 B (pad 256)
    float* T    = (float*)(wsb + 256);              // 1,048,576 B
    float* w2f  = (float*)(wsb + 256 + 1048576);    // 768,000 B
    (void)ws_size;

    // ---- scratch arena at dtype-independent byte window of d_out:
    // bytes [1,048,576 , 21,200,000) lie inside the h output region for BOTH
    // bf16 (h bytes [524288,25100288)) and f32 (h bytes [1048576,50200576)),
    // and are fully overwritten by k_hgemm at the end.
    char* sc = (char*)d_out + 1048576;
    size_t soff = 0;
    auto salloc = [&](size_t nbytes) -> void* {
        void* p = (void*)(sc + soff);
        soff += (nbytes + 255) & ~(size_t)255;
        return p;
    };
    const size_t NV = (size_t)NN * 64;
    float* wA   = (float*)salloc((size_t)274689 * 4);  // 16-segment f32 weight arena
    int*   aCnt = (int*)salloc(NN * 4);
    int*   gCnt = (int*)salloc(NN * 4);
    int*   aIdx = (int*)salloc((size_t)NN * MAXN * 4);
    int*   gIdx = (int*)salloc((size_t)NN * MAXN * 4);
    float* X1  = (float*)salloc(NV * 4);
    float* X2  = (float*)salloc(NV * 4);
    float* Wh1 = (float*)salloc(NV * 4);
    float* Wh2 = (float*)salloc(NV * 4);
    float* A1  = (float*)salloc(NV * 4);
    float* A2  = (float*)salloc(NV * 4);
    float* z   = (float*)salloc(NV * 4);
    float* za  = (float*)salloc(NV * 4);
    float* g   = (float*)salloc(NV * 4);
    float* ga  = (float*)salloc(NV * 4);
    float* De  = (float*)salloc(NV * 4);
    float* Dea = (float*)salloc(NV * 4);
    float* Dg  = (float*)salloc(NV * 4);
    float* Dga = (float*)salloc(NV * 4);
    float* s1  = (float*)salloc(NN * 4);
    float* s2  = (float*)salloc(NN * 4);
    float* d1  = (float*)salloc(NN * 4);
    float* d2  = (float*)salloc(NN * 4);
    // soff ~= 20.1 MB < 20.15 MB window: fits.

    float* w1f   = wA + 0;
    float* attWf = wA + 192000;
    float* asrcf = wA + 196096;
    float* adstf = wA + 196160;
    float* mW1f  = wA + 196224;
    float* mb1f  = wA + 212608;
    float* mW2f  = wA + 212864;
    float* mb2f  = wA + 245632;
    float* mW3f  = wA + 245760;
    float* mb3f  = wA + 253952;
    float* dW1f  = wA + 254016;
    float* db1f  = wA + 262208;
    float* dW2f  = wA + 262336;
    float* db2f  = wA + 270528;
    float* bWf   = wA + 270592;
    float* bbf   = wA + 274688;

    k_detect<<<1, 256, 0, stream>>>((const u16*)feat, flag);
    k_convw<<<dim3(750, 16), 256, 0, stream>>>(flag,
        w1, attW, a_src, a_dst, mW1, mb1, mW2, mb2, mW3, mb3,
        dW1, db1, dW2, db2, bW, bb, wA);
    k_convw2<<<750, 256, 0, stream>>>(flag, w2, w2f);
    k_build_csr<<<dim3(NN, 2), 256, 0, stream>>>(flag, adj, gn, aCnt, aIdx, gCnt, gIdx);
    k_featgemm<<<dim3(NN / 32, 2), 128, 0, stream>>>(flag, feat, feat_a, w1f, X1, X2);
    k_whsd<<<dim3(NN, 2), 64, 0, stream>>>(X1, X2, attWf, asrcf, adstf, Wh1, Wh2, s1, s2, d1, d2);
    k_attn<<<dim3(NN, 2), 128, 0, stream>>>(aCnt, aIdx, s1, s2, d1, d2, Wh1, Wh2, A1, A2);
    k_mlp<<<dim3(NN, 2), 256, 0, stream>>>(flag, A1, A2, mW1f, mb1f, mW2f, mb2f, mW3f, mb3f, z, za, d_out);
    k_readout<<<dim3(NN, 2), 64, 0, stream>>>(gCnt, gIdx, z, za, g, ga);
    k_dmlp<<<dim3(NN, 4), 128, 0, stream>>>(z, za, g, ga, dW1f, db1f, dW2f, db2f, De, Dea, Dg, Dga);
    k_bilin<<<dim3(NN, 4), 64, 0, stream>>>(flag, De, Dea, Dg, Dga, bWf, bbf, d_out);
    k_spmm<<<NN, 64, 0, stream>>>(aCnt, aIdx, z, T);
    k_hgemm<<<512, 256, 0, stream>>>(flag, T, w2f, d_out);   // overwrites arena with real h
}

// Round 5
// 596.976 us; speedup vs baseline: 1.4750x; 1.3243x over previous
//
#include <hip/hip_runtime.h>

#define NN   4096
#define FIN  3000
#define MAXN 128
#define KB   48
#define FSTR 52
#define KSPLIT 10
#define KCH  300

typedef unsigned short u16;

__device__ __forceinline__ float bf2f(u16 u) { union { unsigned int i; float f; } v; v.i = ((unsigned int)u) << 16; return v.f; }
__device__ __forceinline__ u16 f2bf(float f) {
    union { float f; unsigned int i; } v; v.f = f;
    return (u16)((v.i + 0x7FFFu + ((v.i >> 16) & 1u)) >> 16);
}

// ---- dtype detector: bf16 N(0,1) u16s have exponent ~127; f32-as-u16 halves are random.
__global__ __launch_bounds__(1024) void k_detect(const u16* __restrict__ feat, int* __restrict__ flag)
{
    __shared__ int tot;
    if (threadIdx.x == 0) tot = 0;
    __syncthreads();
    int ins = 0;
    for (int i = threadIdx.x; i < 16384; i += 1024) {
        u16 u = feat[i];
        int e = (u >> 7) & 0xFF;
        if (u != 0 && (e < 90 || e > 160)) ins++;
    }
    atomicAdd(&tot, ins);
    __syncthreads();
    if (threadIdx.x == 0) *flag = (tot > 1024) ? 1 : 0;   // 1 = inputs are f32
}

// ---- convert 16 weight tensors -> f32 arena (blockIdx.y = segment) ----
__global__ __launch_bounds__(256) void k_convw(const int* __restrict__ flag,
    const void* s0, const void* s1, const void* s2, const void* s3,
    const void* s4, const void* s5, const void* s6, const void* s7,
    const void* s8, const void* s9, const void* s10, const void* s11,
    const void* s12, const void* s13, const void* s14, const void* s15,
    float* __restrict__ dst)
{
    const void* srcs[16] = {s0,s1,s2,s3,s4,s5,s6,s7,s8,s9,s10,s11,s12,s13,s14,s15};
    const int offs[16] = {0,192000,196096,196160,196224,212608,212864,245632,245760,253952,254016,262208,262336,270528,270592,274688};
    const int ns[16]   = {192000,4096,64,64,16384,256,32768,128,8192,64,8192,128,8192,64,4096,1};
    int seg = blockIdx.y;
    int i = blockIdx.x * 256 + threadIdx.x;
    if (i >= ns[seg]) return;
    float v = (*flag) ? ((const float*)srcs[seg])[i] : bf2f(((const u16*)srcs[seg])[i]);
    dst[offs[seg] + i] = v;
}

// ---- convert weight2 -> f32 in d_ws (survives the arena clobber) ----
__global__ __launch_bounds__(256) void k_convw2(const int* __restrict__ flag,
    const void* __restrict__ src, float* __restrict__ dst)
{
    int i = blockIdx.x * 256 + threadIdx.x;
    if (i >= 192000) return;
    dst[i] = (*flag) ? ((const float*)src)[i] : bf2f(((const u16*)src)[i]);
}

// ---- ordered CSR build (prefix-scan, deterministic, sorted) for adj / graph_neigh ----
__global__ __launch_bounds__(256) void k_build_csr(const int* __restrict__ flag,
    const void* __restrict__ Av, const void* __restrict__ Gv,
    int* __restrict__ aCnt, int* __restrict__ aIdx,
    int* __restrict__ gCnt, int* __restrict__ gIdx)
{
    bool isf = (*flag != 0);
    const void* M = blockIdx.y ? Gv : Av;
    int* cnt = blockIdx.y ? gCnt : aCnt;
    int* idx = blockIdx.y ? gIdx : aIdx;
    int row = blockIdx.x, t = threadIdx.x;
    int c0 = t * 16;
    unsigned int mask = 0; int my = 0;
    if (isf) {
        const float* r = (const float*)M + (size_t)row * NN + c0;
        #pragma unroll
        for (int j = 0; j < 16; j++) if (r[j] != 0.f) { mask |= 1u << j; my++; }
    } else {
        const u16* r = (const u16*)M + (size_t)row * NN + c0;
        #pragma unroll
        for (int j = 0; j < 16; j++) if (r[j] != 0) { mask |= 1u << j; my++; }
    }
    __shared__ int sc[256];
    sc[t] = my;
    __syncthreads();
    for (int d = 1; d < 256; d <<= 1) {
        int v = (t >= d) ? sc[t - d] : 0;
        __syncthreads();
        sc[t] += v;
        __syncthreads();
    }
    int pos = sc[t] - my;
    for (int j = 0; j < 16; j++) {
        if (mask & (1u << j)) {
            if (pos < MAXN) idx[(size_t)row * MAXN + pos] = c0 + j;
            pos++;
        }
    }
    if (t == 0) { int total = sc[255]; cnt[row] = (total < MAXN) ? total : MAXN; }
}

// ---- X += feat @ weight1, split-K: grid (rowtiles, KSPLIT, 2), atomic accumulate ----
__global__ __launch_bounds__(128) void k_featgemm(const int* __restrict__ flag,
    const void* __restrict__ F0v, const void* __restrict__ F1v,
    const float* __restrict__ W1f, float* __restrict__ X0, float* __restrict__ X1)
{
    bool isf = (*flag != 0);
    const void* Fv = blockIdx.z ? F1v : F0v;
    float* X = blockIdx.z ? X1 : X0;
    int r0 = blockIdx.x * 32;
    int kbeg = blockIdx.y * KCH;
    int kend = kbeg + KCH;                 // 3000 = 10*300, no clamp needed
    int tid = threadIdx.x;
    int cg = tid & 15, rg = tid >> 4;      // 16 col-groups x 8 row-groups
    int c0 = cg * 4, rr = rg * 4;
    __shared__ float Wl[KB * 64];          // [kk][c], 12288 B
    __shared__ float Fl[32 * FSTR];        // [row][kk], pad 52
    float acc[4][4] = {};
    for (int k0 = kbeg; k0 < kend; k0 += KB) {
        int rem = kend - k0;
        int nk = rem < KB ? rem : KB;      // 48 or 12 (tail of each 300-chunk)
        __syncthreads();
        {
            const float4* g = (const float4*)(W1f + (size_t)k0 * 64);
            int nf4 = nk * 16;
            #pragma unroll
            for (int j = 0; j < 6; j++) {
                int i = tid + 128 * j;     // [0,768)
                float4 v = {0.f, 0.f, 0.f, 0.f};
                if (i < nf4) v = g[i];
                ((float4*)Wl)[i] = v;
            }
        }
        if (isf) {
            const float* F = (const float*)Fv;
            #pragma unroll
            for (int j = 0; j < 3; j++) {
                int i = tid + 128 * j;     // [0,384), 12 f4 per row
                int row = i / 12, c4 = i % 12;
                int kk = c4 * 4;
                float4 v = {0.f, 0.f, 0.f, 0.f};
                if (kk < nk) v = *(const float4*)(F + (size_t)(r0 + row) * FIN + k0 + kk);
                *(float4*)(Fl + row * FSTR + kk) = v;
            }
        } else {
            const u16* F = (const u16*)Fv;
            for (int i = tid; i < 32 * KB; i += 128) {
                int row = i / KB, kk = i % KB;
                float v = 0.f;
                if (kk < nk) v = bf2f(F[(size_t)(r0 + row) * FIN + k0 + kk]);
                Fl[row * FSTR + kk] = v;
            }
        }
        __syncthreads();
        #pragma unroll
        for (int q = 0; q < KB; q += 4) {
            float4 w0 = *(float4*)(Wl + (q + 0) * 64 + c0);
            float4 w1 = *(float4*)(Wl + (q + 1) * 64 + c0);
            float4 w2 = *(float4*)(Wl + (q + 2) * 64 + c0);
            float4 w3 = *(float4*)(Wl + (q + 3) * 64 + c0);
            #pragma unroll
            for (int i = 0; i < 4; i++) {
                float4 f = *(float4*)(Fl + (rr + i) * FSTR + q);
                acc[i][0] += f.x * w0.x + f.y * w1.x + f.z * w2.x + f.w * w3.x;
                acc[i][1] += f.x * w0.y + f.y * w1.y + f.z * w2.y + f.w * w3.y;
                acc[i][2] += f.x * w0.z + f.y * w1.z + f.z * w2.z + f.w * w3.z;
                acc[i][3] += f.x * w0.w + f.y * w1.w + f.z * w2.w + f.w * w3.w;
            }
        }
    }
    #pragma unroll
    for (int i = 0; i < 4; i++) {
        float* xp = X + (size_t)(r0 + rr + i) * 64 + c0;
        atomicAdd(xp + 0, acc[i][0]);
        atomicAdd(xp + 1, acc[i][1]);
        atomicAdd(xp + 2, acc[i][2]);
        atomicAdd(xp + 3, acc[i][3]);
    }
}

// ---- Wh = X @ att_W; s = Wh@a_src; d = Wh@a_dst (all-f32) ----
__global__ __launch_bounds__(64) void k_whsd(
    const float* __restrict__ X1, const float* __restrict__ X2,
    const float* __restrict__ AW, const float* __restrict__ asrc, const float* __restrict__ adst,
    float* __restrict__ Wh1, float* __restrict__ Wh2,
    float* __restrict__ s1, float* __restrict__ s2,
    float* __restrict__ d1, float* __restrict__ d2)
{
    const float* X = blockIdx.y ? X2 : X1;
    float* Wh = blockIdx.y ? Wh2 : Wh1;
    float* sv = blockIdx.y ? s2 : s1;
    float* dv = blockIdx.y ? d2 : d1;
    int row = blockIdx.x, c = threadIdx.x;
    __shared__ float x[64];
    x[c] = X[(size_t)row * 64 + c];
    __syncthreads();
    float acc = 0.f;
    #pragma unroll 16
    for (int k = 0; k < 64; k++) acc += x[k] * AW[k * 64 + c];
    Wh[(size_t)row * 64 + c] = acc;
    float vs = acc * asrc[c];
    float vd = acc * adst[c];
    #pragma unroll
    for (int off = 32; off > 0; off >>= 1) { vs += __shfl_down(vs, off); vd += __shfl_down(vd, off); }
    if (c == 0) { sv[row] = vs; dv[row] = vd; }
}

// ---- masked softmax (rank-1 scores) + P @ Wh over CSR neighbors ----
__global__ __launch_bounds__(128) void k_attn(
    const int* __restrict__ cnt, const int* __restrict__ idx,
    const float* __restrict__ s1, const float* __restrict__ s2,
    const float* __restrict__ d1, const float* __restrict__ d2,
    const float* __restrict__ Wh1, const float* __restrict__ Wh2,
    float* __restrict__ A1, float* __restrict__ A2)
{
    const float* sp = blockIdx.y ? s2 : s1;
    const float* dp = blockIdx.y ? d2 : d1;
    const float* Wh = blockIdx.y ? Wh2 : Wh1;
    float* A = blockIdx.y ? A2 : A1;
    int row = blockIdx.x, tid = threadIdx.x;
    int n = cnt[row];
    __shared__ int js[MAXN];
    __shared__ float ps[MAXN];
    __shared__ float red2[2];
    __shared__ float ared[2][64];
    for (int k = tid; k < n; k += 128) js[k] = idx[(size_t)row * MAXN + k];
    __syncthreads();
    float si = sp[row];
    float m = -3.0e38f;
    for (int k = tid; k < n; k += 128) {
        float e = si + dp[js[k]];
        e = e > 0.f ? e : 0.2f * e;   // LeakyReLU(0.2)
        ps[k] = e;
        m = fmaxf(m, e);
    }
    #pragma unroll
    for (int off = 32; off > 0; off >>= 1) m = fmaxf(m, __shfl_down(m, off));
    if ((tid & 63) == 0) red2[tid >> 6] = m;
    __syncthreads();
    m = fmaxf(red2[0], red2[1]);
    __syncthreads();
    float zz = 0.f;
    for (int k = tid; k < n; k += 128) {
        float p = __expf(ps[k] - m);
        ps[k] = p;
        zz += p;
    }
    #pragma unroll
    for (int off = 32; off > 0; off >>= 1) zz += __shfl_down(zz, off);
    if ((tid & 63) == 0) red2[tid >> 6] = zz;
    __syncthreads();
    float Z = red2[0] + red2[1];
    Z = fmaxf(Z, 1e-20f);           // guard 0/0
    int f = tid & 63, half = tid >> 6;
    float acc = 0.f;
    for (int k = half; k < n; k += 2) acc += ps[k] * Wh[(size_t)js[k] * 64 + f];
    ared[half][f] = acc;
    __syncthreads();
    if (tid < 64) A[(size_t)row * 64 + f] = (ared[0][f] + ared[1][f]) / Z;
}

// ---- 3-layer MLP 64->256->128->64; 4 rows/block; writes z (f32) and hiden_emb (dual-dtype, y==0) ----
__global__ __launch_bounds__(256) void k_mlp(const int* __restrict__ flag,
    const float* __restrict__ A1, const float* __restrict__ A2,
    const float* __restrict__ W1, const float* __restrict__ b1,
    const float* __restrict__ W2, const float* __restrict__ b2,
    const float* __restrict__ W3, const float* __restrict__ b3,
    float* __restrict__ Z1, float* __restrict__ Z2, void* __restrict__ hidenv)
{
    const float* A = blockIdx.y ? A2 : A1;
    float* Z = blockIdx.y ? Z2 : Z1;
    int row0 = blockIdx.x * 4, tid = threadIdx.x;
    __shared__ float x[4][64], h1[4][256], h2[4][128];
    {
        int r = tid >> 6, c = tid & 63;
        x[r][c] = A[(size_t)(row0 + r) * 64 + c];
    }
    __syncthreads();
    {
        float a0 = b1[tid], a1v = a0, a2v = a0, a3v = a0;
        #pragma unroll 8
        for (int k = 0; k < 64; k++) {
            float w = W1[k * 256 + tid];
            a0 += x[0][k] * w; a1v += x[1][k] * w; a2v += x[2][k] * w; a3v += x[3][k] * w;
        }
        h1[0][tid] = fmaxf(a0, 0.f);  h1[1][tid] = fmaxf(a1v, 0.f);
        h1[2][tid] = fmaxf(a2v, 0.f); h1[3][tid] = fmaxf(a3v, 0.f);
    }
    __syncthreads();
    if (tid < 128) {
        float a0 = b2[tid], a1v = a0, a2v = a0, a3v = a0;
        #pragma unroll 8
        for (int k = 0; k < 256; k++) {
            float w = W2[k * 128 + tid];
            a0 += h1[0][k] * w; a1v += h1[1][k] * w; a2v += h1[2][k] * w; a3v += h1[3][k] * w;
        }
        h2[0][tid] = fmaxf(a0, 0.f);  h2[1][tid] = fmaxf(a1v, 0.f);
        h2[2][tid] = fmaxf(a2v, 0.f); h2[3][tid] = fmaxf(a3v, 0.f);
    }
    __syncthreads();
    if (tid < 64) {
        float a[4];
        a[0] = a[1] = a[2] = a[3] = b3[tid];
        #pragma unroll 8
        for (int k = 0; k < 128; k++) {
            float w = W3[k * 64 + tid];
            a[0] += h2[0][k] * w; a[1] += h2[1][k] * w; a[2] += h2[2][k] * w; a[3] += h2[3][k] * w;
        }
        bool isf = (*flag != 0);
        #pragma unroll
        for (int r = 0; r < 4; r++) {
            size_t ei = (size_t)(row0 + r) * 64 + tid;
            Z[ei] = a[r];
            if (blockIdx.y == 0) {
                if (isf) ((float*)hidenv)[ei] = a[r];
                else     ((u16*)hidenv)[ei] = f2bf(a[r]);
            }
        }
    }
}

// ---- T = adj @ z over CSR ----
__global__ __launch_bounds__(64) void k_spmm(
    const int* __restrict__ cnt, const int* __restrict__ idx,
    const float* __restrict__ Z, float* __restrict__ T)
{
    int row = blockIdx.x, f = threadIdx.x;
    int n = cnt[row];
    const int* ir = idx + (size_t)row * MAXN;
    float acc = 0.f;
    for (int k = 0; k < n; k++) acc += Z[(size_t)ir[k] * 64 + f];
    T[(size_t)row * 64 + f] = acc;
}

// ---- H = T @ weight2 -> out (dual-dtype store), 8 rows/block ----
__global__ __launch_bounds__(256) void k_hgemm(const int* __restrict__ flag,
    const float* __restrict__ T, const float* __restrict__ W2f, void* __restrict__ outv)
{
    bool isf = (*flag != 0);
    int r0 = blockIdx.x * 8, tid = threadIdx.x;
    __shared__ float tt[8][64];
    for (int i = tid; i < 512; i += 256) tt[i >> 6][i & 63] = T[(size_t)r0 * 64 + i];
    __syncthreads();
    for (int c = tid; c < FIN; c += 256) {
        float a[8] = {0,0,0,0,0,0,0,0};
        #pragma unroll 8
        for (int k = 0; k < 64; k++) {
            float w = W2f[(size_t)k * FIN + c];
            #pragma unroll
            for (int i = 0; i < 8; i++) a[i] += tt[i][k] * w;
        }
        #pragma unroll
        for (int i = 0; i < 8; i++) {
            size_t ei = 262144 + (size_t)(r0 + i) * FIN + c;
            if (isf) ((float*)outv)[ei] = a[i];
            else     ((u16*)outv)[ei] = f2bf(a[i]);
        }
    }
}

// ---- readout: mean over graph_neigh nbrs of relu(z), L2 normalize, sigmoid ----
__global__ __launch_bounds__(64) void k_readout(
    const int* __restrict__ cnt, const int* __restrict__ idx,
    const float* __restrict__ Z1, const float* __restrict__ Z2,
    float* __restrict__ G1, float* __restrict__ G2)
{
    const float* Z = blockIdx.y ? Z2 : Z1;
    float* G = blockIdx.y ? G2 : G1;
    int row = blockIdx.x, f = threadIdx.x;
    int n = cnt[row];
    const int* ir = idx + (size_t)row * MAXN;
    float acc = 0.f;
    for (int k = 0; k < n; k++) acc += fmaxf(Z[(size_t)ir[k] * 64 + f], 0.f);
    acc /= (float)(n > 0 ? n : 1);
    float sq = acc * acc;
    #pragma unroll
    for (int off = 32; off > 0; off >>= 1) sq += __shfl_down(sq, off);
    sq = __shfl(sq, 0);
    float nrm = fmaxf(sqrtf(sq), 1e-12f);
    float v = acc / nrm;
    G[(size_t)row * 64 + f] = 1.f / (1.f + __expf(-v));
}

// ---- discriminator MLP 64->128->64; 4 rows/block; on {relu(z), relu(z_a), g, g_a} ----
__global__ __launch_bounds__(128) void k_dmlp(
    const float* __restrict__ z, const float* __restrict__ za,
    const float* __restrict__ g, const float* __restrict__ ga,
    const float* __restrict__ W1, const float* __restrict__ b1,
    const float* __restrict__ W2, const float* __restrict__ b2,
    float* __restrict__ De, float* __restrict__ Dea,
    float* __restrict__ Dg, float* __restrict__ Dga)
{
    int w = blockIdx.y;
    const float* X = (w == 0) ? z : (w == 1) ? za : (w == 2) ? g : ga;
    float* O = (w == 0) ? De : (w == 1) ? Dea : (w == 2) ? Dg : Dga;
    int doRelu = (w < 2);
    int row0 = blockIdx.x * 4, tid = threadIdx.x;
    __shared__ float x[4][64], h1[4][128];
    for (int i = tid; i < 256; i += 128) {
        int r = i >> 6, c = i & 63;
        float v = X[(size_t)(row0 + r) * 64 + c];
        x[r][c] = doRelu ? fmaxf(v, 0.f) : v;
    }
    __syncthreads();
    {
        float a0 = b1[tid], a1v = a0, a2v = a0, a3v = a0;
        #pragma unroll 8
        for (int k = 0; k < 64; k++) {
            float w_ = W1[k * 128 + tid];
            a0 += x[0][k] * w_; a1v += x[1][k] * w_; a2v += x[2][k] * w_; a3v += x[3][k] * w_;
        }
        h1[0][tid] = fmaxf(a0, 0.f);  h1[1][tid] = fmaxf(a1v, 0.f);
        h1[2][tid] = fmaxf(a2v, 0.f); h1[3][tid] = fmaxf(a3v, 0.f);
    }
    __syncthreads();
    if (tid < 64) {
        float a[4];
        a[0] = a[1] = a[2] = a[3] = b2[tid];
        #pragma unroll 8
        for (int k = 0; k < 128; k++) {
            float w_ = W2[k * 64 + tid];
            a[0] += h1[0][k] * w_; a[1] += h1[1][k] * w_; a[2] += h1[2][k] * w_; a[3] += h1[3][k] * w_;
        }
        #pragma unroll
        for (int r = 0; r < 4; r++) O[(size_t)(row0 + r) * 64 + tid] = a[r];
    }
}

// ---- bilinear: out = x . (bil_W @ y) + b ; dual-dtype store ----
__global__ __launch_bounds__(64) void k_bilin(const int* __restrict__ flag,
    const float* __restrict__ De, const float* __restrict__ Dea,
    const float* __restrict__ Dg, const float* __restrict__ Dga,
    const float* __restrict__ BW, const float* __restrict__ bb, void* __restrict__ outv)
{
    int w = blockIdx.y;
    const float* X = (w == 0 || w == 3) ? De : Dea;
    const float* Y = (w <= 1) ? Dg : Dga;
    size_t bse = (w <= 1) ? (size_t)12550144 : (size_t)12558336;
    int col = (w == 0 || w == 2) ? 0 : 1;
    int row = blockIdx.x, k = threadIdx.x;
    __shared__ float x[64], y[64];
    x[k] = X[(size_t)row * 64 + k];
    y[k] = Y[(size_t)row * 64 + k];
    __syncthreads();
    float wv = 0.f;
    #pragma unroll 8
    for (int j = 0; j < 64; j++) wv += BW[k * 64 + j] * y[j];
    float v = x[k] * wv;
    #pragma unroll
    for (int off = 32; off > 0; off >>= 1) v += __shfl_down(v, off);
    if (k == 0) {
        float r = v + bb[0];
        size_t ei = bse + (size_t)row * 2 + col;
        if (*flag) ((float*)outv)[ei] = r;
        else       ((u16*)outv)[ei] = f2bf(r);
    }
}

extern "C" void kernel_launch(void* const* d_in, const int* in_sizes, int n_in,
                              void* d_out, int out_size, void* d_ws, size_t ws_size,
                              hipStream_t stream) {
    const void* feat   = d_in[0];
    const void* feat_a = d_in[1];
    const void* adj    = d_in[2];
    const void* gn     = d_in[3];
    const void* w1     = d_in[4];
    const void* w2     = d_in[5];
    const void* attW   = d_in[6];
    const void* a_src  = d_in[7];
    const void* a_dst  = d_in[8];
    const void* mW1    = d_in[9];
    const void* mb1    = d_in[10];
    const void* mW2    = d_in[11];
    const void* mb2    = d_in[12];
    const void* mW3    = d_in[13];
    const void* mb3    = d_in[14];
    const void* dW1    = d_in[15];
    const void* db1    = d_in[16];
    const void* dW2    = d_in[17];
    const void* db2    = d_in[18];
    const void* bW     = d_in[19];
    const void* bb     = d_in[20];
    (void)in_sizes; (void)n_in; (void)out_size;

    // ---- d_ws: flag + T + w2f  (~1.8 MB total; minimal footprint) ----
    char* wsb = (char*)d_ws;
    int*   flag = (int*)wsb;                        // 4 B (pad 256)
    float* T    = (float*)(wsb + 256);              // 1,048,576 B
    float* w2f  = (float*)(wsb + 256 + 1048576);    // 768,000 B
    (void)ws_size;

    // ---- scratch arena at dtype-independent byte window of d_out:
    // bytes [1,048,576 , 21,200,000) lie inside the h output region for BOTH
    // bf16 (h bytes [524288,25100288)) and f32 (h bytes [1048576,50200576)),
    // and are fully overwritten by k_hgemm at the end.
    char* sc = (char*)d_out + 1048576;
    size_t soff = 0;
    auto salloc = [&](size_t nbytes) -> void* {
        void* p = (void*)(sc + soff);
        soff += (nbytes + 255) & ~(size_t)255;
        return p;
    };
    const size_t NV = (size_t)NN * 64;
    float* wA   = (float*)salloc((size_t)274689 * 4);  // 16-segment f32 weight arena
    int*   aCnt = (int*)salloc(NN * 4);
    int*   gCnt = (int*)salloc(NN * 4);
    int*   aIdx = (int*)salloc((size_t)NN * MAXN * 4);
    int*   gIdx = (int*)salloc((size_t)NN * MAXN * 4);
    float* X1  = (float*)salloc(NV * 4);
    float* X2  = (float*)salloc(NV * 4);   // contiguous with X1 (NV*4 is 256-mult)
    float* Wh1 = (float*)salloc(NV * 4);
    float* Wh2 = (float*)salloc(NV * 4);
    float* A1  = (float*)salloc(NV * 4);
    float* A2  = (float*)salloc(NV * 4);
    float* z   = (float*)salloc(NV * 4);
    float* za  = (float*)salloc(NV * 4);
    float* g   = (float*)salloc(NV * 4);
    float* ga  = (float*)salloc(NV * 4);
    float* De  = (float*)salloc(NV * 4);
    float* Dea = (float*)salloc(NV * 4);
    float* Dg  = (float*)salloc(NV * 4);
    float* Dga = (float*)salloc(NV * 4);
    float* s1  = (float*)salloc(NN * 4);
    float* s2  = (float*)salloc(NN * 4);
    float* d1  = (float*)salloc(NN * 4);
    float* d2  = (float*)salloc(NN * 4);
    // soff ~= 20.1 MB < 20.15 MB window: fits.

    float* w1f   = wA + 0;
    float* attWf = wA + 192000;
    float* asrcf = wA + 196096;
    float* adstf = wA + 196160;
    float* mW1f  = wA + 196224;
    float* mb1f  = wA + 212608;
    float* mW2f  = wA + 212864;
    float* mb2f  = wA + 245632;
    float* mW3f  = wA + 245760;
    float* mb3f  = wA + 253952;
    float* dW1f  = wA + 254016;
    float* db1f  = wA + 262208;
    float* dW2f  = wA + 262336;
    float* db2f  = wA + 270528;
    float* bWf   = wA + 270592;
    float* bbf   = wA + 274688;

    k_detect<<<1, 1024, 0, stream>>>((const u16*)feat, flag);
    k_convw<<<dim3(750, 16), 256, 0, stream>>>(flag,
        w1, attW, a_src, a_dst, mW1, mb1, mW2, mb2, mW3, mb3,
        dW1, db1, dW2, db2, bW, bb, wA);
    k_convw2<<<750, 256, 0, stream>>>(flag, w2, w2f);
    k_build_csr<<<dim3(NN, 2), 256, 0, stream>>>(flag, adj, gn, aCnt, aIdx, gCnt, gIdx);
    hipMemsetAsync(X1, 0, 2 * NV * 4, stream);   // zero X1+X2 for split-K atomics
    k_featgemm<<<dim3(NN / 32, KSPLIT, 2), 128, 0, stream>>>(flag, feat, feat_a, w1f, X1, X2);
    k_whsd<<<dim3(NN, 2), 64, 0, stream>>>(X1, X2, attWf, asrcf, adstf, Wh1, Wh2, s1, s2, d1, d2);
    k_attn<<<dim3(NN, 2), 128, 0, stream>>>(aCnt, aIdx, s1, s2, d1, d2, Wh1, Wh2, A1, A2);
    k_mlp<<<dim3(NN / 4, 2), 256, 0, stream>>>(flag, A1, A2, mW1f, mb1f, mW2f, mb2f, mW3f, mb3f, z, za, d_out);
    k_readout<<<dim3(NN, 2), 64, 0, stream>>>(gCnt, gIdx, z, za, g, ga);
    k_dmlp<<<dim3(NN / 4, 4), 128, 0, stream>>>(z, za, g, ga, dW1f, db1f, dW2f, db2f, De, Dea, Dg, Dga);
    k_bilin<<<dim3(NN, 4), 64, 0, stream>>>(flag, De, Dea, Dg, Dga, bWf, bbf, d_out);
    k_spmm<<<NN, 64, 0, stream>>>(aCnt, aIdx, z, T);
    k_hgemm<<<512, 256, 0, stream>>>(flag, T, w2f, d_out);   // overwrites arena with real h
}